// Round 14
// baseline (4379.586 us; speedup 1.0000x reference)
//
#include <hip/hip_runtime.h>
#include <hip/hip_bf16.h>
#include <math.h>
#include <stdint.h>

typedef unsigned short u16;
typedef __bf16 bf16x8 __attribute__((ext_vector_type(8)));
typedef float f32x4 __attribute__((ext_vector_type(4)));
typedef __attribute__((address_space(1))) void gv_t;
typedef __attribute__((address_space(3))) void lv_t;

// ---------- helpers ----------
__device__ inline u16 f2bf(float f) {
    union { float f; uint32_t u; } v; v.f = f;
    uint32_t u = v.u;
    uint32_t r = (u + 0x7fffu + ((u >> 16) & 1u)) >> 16;  // RNE
    return (u16)r;
}
__device__ inline float gelu_tanh(float x) {
    float u = 0.7978845608028654f * x * (1.0f + 0.044715f * x * x);
    float e = __expf(2.0f * u);
    float t = 1.0f - 2.0f / (e + 1.0f);
    return 0.5f * x * (1.0f + t);
}

// ---------- gate ----------
__global__ __launch_bounds__(256) void gate_kernel(const float* __restrict__ x,
                                                   const float* __restrict__ Wg,
                                                   float* __restrict__ w4) {
    const int token = blockIdx.x * 4 + (threadIdx.x >> 6);
    const int lane  = threadIdx.x & 63;
    const float* xr = x + (size_t)token * 1024;
    float acc[16];
#pragma unroll
    for (int e = 0; e < 16; e++) acc[e] = 0.f;
#pragma unroll 4
    for (int d = lane; d < 1024; d += 64) {
        float xv = xr[d];
        const float4* wr_ = (const float4*)(Wg + (size_t)d * 16);
        float4 a0 = wr_[0], a1 = wr_[1], a2 = wr_[2], a3 = wr_[3];
        acc[0]  += xv * a0.x; acc[1]  += xv * a0.y; acc[2]  += xv * a0.z; acc[3]  += xv * a0.w;
        acc[4]  += xv * a1.x; acc[5]  += xv * a1.y; acc[6]  += xv * a1.z; acc[7]  += xv * a1.w;
        acc[8]  += xv * a2.x; acc[9]  += xv * a2.y; acc[10] += xv * a2.z; acc[11] += xv * a2.w;
        acc[12] += xv * a3.x; acc[13] += xv * a3.y; acc[14] += xv * a3.z; acc[15] += xv * a3.w;
    }
#pragma unroll
    for (int e = 0; e < 16; e++) {
        float v = acc[e];
        v += __shfl_xor(v, 32, 64);
        v += __shfl_xor(v, 16, 64);
        v += __shfl_xor(v, 8, 64);
        v += __shfl_xor(v, 4, 64);
        v += __shfl_xor(v, 2, 64);
        v += __shfl_xor(v, 1, 64);
        acc[e] = v;
    }
    if (lane == 0) {
        float l[16];
#pragma unroll
        for (int e = 0; e < 16; e++) l[e] = acc[e];
        int   bi4[4]; float bv4[4];
#pragma unroll
        for (int j = 0; j < 4; j++) {
            int bi = 0; float b = l[0];
#pragma unroll
            for (int e = 1; e < 16; e++) { if (l[e] > b) { b = l[e]; bi = e; } }
            bi4[j] = bi; bv4[j] = b; l[bi] = -INFINITY;
        }
        float mx = bv4[0];
        float den = 0.f;
#pragma unroll
        for (int j = 0; j < 4; j++) den += expf(bv4[j] - mx);
        float wout[4] = {0.f, 0.f, 0.f, 0.f};
#pragma unroll
        for (int j = 0; j < 4; j++)
            if (bi4[j] < 4) wout[bi4[j]] = expf(bv4[j] - mx) / den;
        float* o = w4 + (size_t)token * 4;
        o[0] = wout[0]; o[1] = wout[1]; o[2] = wout[2]; o[3] = wout[3];
    }
}

// ---------- vectorized cast x fp32 -> bf16 ----------
__global__ __launch_bounds__(256) void cast_x_kernel(const float* __restrict__ x,
                                                     u16* __restrict__ Xe, int nvec) {
    for (int i = blockIdx.x * blockDim.x + threadIdx.x; i < nvec; i += gridDim.x * blockDim.x) {
        const float4* s = (const float4*)(x + (size_t)i * 8);
        float4 a = s[0], b = s[1];
        union { u16 h[8]; uint4 q; } o;
        o.h[0] = f2bf(a.x); o.h[1] = f2bf(a.y); o.h[2] = f2bf(a.z); o.h[3] = f2bf(a.w);
        o.h[4] = f2bf(b.x); o.h[5] = f2bf(b.y); o.h[6] = f2bf(b.z); o.h[7] = f2bf(b.w);
        *(uint4*)(Xe + (size_t)i * 8) = o.q;
    }
}

// ---------- fused transpose + LoRA-fold ----------
__global__ __launch_bounds__(256) void weff_kernel(const float* __restrict__ src,
                                                   const float* __restrict__ Am,
                                                   const float* __restrict__ Bm,
                                                   u16* __restrict__ dst,
                                                   int Fdim, int lddst,
                                                   size_t s_est, size_t a_est, size_t b_est, size_t d_est) {
    const int e = blockIdx.z;
    src += e * s_est; Am += e * a_est; Bm += e * b_est; dst += e * d_est;
    __shared__ float t[32][33];
    __shared__ float sa[32][16];
    __shared__ float sb[16][32];
    const int tx = threadIdx.x, ty = threadIdx.y, tid = ty * 32 + tx;
    const int f0 = blockIdx.x * 32, k0 = blockIdx.y * 32;
#pragma unroll
    for (int i = ty; i < 32; i += 8) t[i][tx] = src[(size_t)(k0 + i) * Fdim + f0 + tx];
    for (int idx = tid; idx < 512; idx += 256) sa[idx >> 4][idx & 15] = Am[(size_t)(k0 + (idx >> 4)) * 16 + (idx & 15)];
    for (int idx = tid; idx < 512; idx += 256) sb[idx >> 5][idx & 31] = Bm[(size_t)(idx >> 5) * Fdim + f0 + (idx & 31)];
    __syncthreads();
#pragma unroll
    for (int i = ty; i < 32; i += 8) {
        float s = t[tx][i];
#pragma unroll
        for (int r = 0; r < 16; r++) s += sa[tx][r] * sb[r][i];
        dst[(size_t)(f0 + i) * lddst + k0 + tx] = f2bf(s);
    }
}

// ---------- out += p1 + p2 + p3 ----------
__global__ __launch_bounds__(256) void add3_kernel(float* __restrict__ out,
                                                   const float* __restrict__ p1,
                                                   const float* __restrict__ p2,
                                                   const float* __restrict__ p3, int n4) {
    for (int i = blockIdx.x * blockDim.x + threadIdx.x; i < n4; i += gridDim.x * blockDim.x) {
        float4 o = ((float4*)out)[i];
        float4 a = ((const float4*)p1)[i];
        float4 b = ((const float4*)p2)[i];
        float4 c = ((const float4*)p3)[i];
        o.x += a.x + b.x + c.x; o.y += a.y + b.y + c.y;
        o.z += a.z + b.z + c.z; o.w += a.w + b.w + c.w;
        ((float4*)out)[i] = o;
    }
}

// ---------- out += p0 + p1 + p2 + p3 ----------
__global__ __launch_bounds__(256) void add4_kernel(float* __restrict__ out,
                                                   const float* __restrict__ p0,
                                                   const float* __restrict__ p1,
                                                   const float* __restrict__ p2,
                                                   const float* __restrict__ p3, int n4) {
    for (int i = blockIdx.x * blockDim.x + threadIdx.x; i < n4; i += gridDim.x * blockDim.x) {
        float4 o = ((float4*)out)[i];
        float4 z = ((const float4*)p0)[i];
        float4 a = ((const float4*)p1)[i];
        float4 b = ((const float4*)p2)[i];
        float4 c = ((const float4*)p3)[i];
        o.x += z.x + a.x + b.x + c.x; o.y += z.y + a.y + b.y + c.y;
        o.z += z.z + a.z + b.z + c.z; o.w += z.w + a.w + b.w + c.w;
        ((float4*)out)[i] = o;
    }
}

// ================= co-resident GEMM (r14): 256x256 tile, BK=32, 64 KB LDS =================
// 2 buffers x (A 256x32 + B 256x32) = 64 KB -> TWO blocks co-resident per CU
// (launch_bounds(512,4) caps VGPR at 128 -> 4 waves/SIMD). 8 waves 2Mx4N.
// Per 32-K tile: 2 phases x 16 MFMA; stage(t+1) (8 gloads) issued in phase 0;
// vmcnt(0) at tile top (stages(t) issued ~3/4 tile earlier; residual latency is
// hidden by the partner block). LDS layout identical to r4/r5-verified 0-conflict:
// 2 rows per 128B line, phys 16B chunk = ((row&1)*4 + kchunk) ^ (line&7).
#define LOADA(BUF, AQ)                                                         \
    _Pragma("unroll") for (int mi = 0; mi < 4; mi++)                           \
        a[mi] = *(const bf16x8*)&As[(BUF)*8192 + wr*4096 + (AQ)*2048 + mi*512 + lfrag];
#define LOADB(BUF)                                                             \
    _Pragma("unroll") for (int nf = 0; nf < 4; nf++)                           \
        b[nf] = *(const bf16x8*)&Bs[(BUF)*8192 + wc*2048 + nf*512 + lfrag];
#define BAR __builtin_amdgcn_s_barrier();
#define MFQ(Q)                                                                 \
    __builtin_amdgcn_s_setprio(1);                                             \
    _Pragma("unroll") for (int mi = 0; mi < 4; mi++)                           \
    _Pragma("unroll") for (int nf = 0; nf < 4; nf++)                           \
        acc[(Q)*4+mi][nf] = __builtin_amdgcn_mfma_f32_16x16x32_bf16(           \
            a[mi], b[nf], acc[(Q)*4+mi][nf], 0, 0, 0);                         \
    __builtin_amdgcn_s_setprio(0);
#define VMW0 asm volatile("s_waitcnt vmcnt(0)" ::: "memory");

#define GEMM_BODY(NT)                                                          \
    stage_a(0, 0); stage_a(0, 1); stage_b(0, 0); stage_b(0, 1);                \
    for (int t = 0; t < (NT); ++t) {                                           \
        const int buf = t & 1;                                                 \
        const bool pf = (t + 1 < (NT));                                        \
        VMW0 BAR                                                               \
        LOADA(buf, 0) LOADB(buf)                                               \
        if (pf) { stage_a(t + 1, 0); stage_a(t + 1, 1);                        \
                  stage_b(t + 1, 0); stage_b(t + 1, 1); }                      \
        BAR                                                                    \
        MFQ(0)                                                                 \
        BAR                                                                    \
        LOADA(buf, 1)                                                          \
        BAR                                                                    \
        MFQ(1)                                                                 \
    }

// ---------- GEMM1: Hout = bf16(w4*gelu(A @ BT^T)); XCD-owned tn (r12 mapping) ----------
__global__ __launch_bounds__(512, 4) void gemm1_kernel(
    const u16* __restrict__ A, const u16* __restrict__ BT,
    u16* __restrict__ Hout, const float* __restrict__ w4, const int ebase) {
    const int lda = 1024, ldb = 1024, ldh = 8192;
    __shared__ __align__(16) u16 As[16384];
    __shared__ __align__(16) u16 Bs[16384];
    const int tid = threadIdx.x;
    const int w = tid >> 6, lane = tid & 63;
    const int wr = w >> 2, wc = w & 3;

    const int xcd = (int)blockIdx.x & 7;
    const int local = (int)blockIdx.x >> 3;
    const int tn = xcd * 4 + (local & 3);
    const int tm = local >> 2;

    // staging addressing (linear LDS dest, inverse-swizzled global source)
    const int il = lane >> 3;
    const int cch = (lane & 7) ^ il;
    const int rowoff = il * 2 + (cch >> 2);
    const int kch = cch & 3;
    const u16* gA0 = A  + (size_t)(tm * 256 + w * 16 + rowoff) * lda + kch * 8;
    const u16* gB0 = BT + (size_t)(tn * 256 + w * 16 + rowoff) * ldb + kch * 8;

    // fragment read lane offset
    const int rr = lane & 15, kq = lane >> 4;
    const int lfrag = (rr >> 1) * 64 + (((((rr & 1) << 2) | kq) ^ ((rr >> 1) & 7)) << 3);

    f32x4 acc[8][4];
#pragma unroll
    for (int mi = 0; mi < 8; mi++)
#pragma unroll
        for (int nf = 0; nf < 4; nf++) acc[mi][nf] = (f32x4){0.f, 0.f, 0.f, 0.f};
    bf16x8 a[4], b[4];

    auto stage_a = [&](int tile, int half) {
        const int dst = (tile & 1) * 8192 + half * 4096 + w * 512;
        const u16* src = gA0 + (size_t)half * 128 * lda + (size_t)tile * 32;
        __builtin_amdgcn_global_load_lds((gv_t*)(u16*)src, (lv_t*)&As[dst], 16, 0, 0);
    };
    auto stage_b = [&](int tile, int half) {
        const int dst = (tile & 1) * 8192 + half * 4096 + w * 512;
        const u16* src = gB0 + (size_t)half * 128 * ldb + (size_t)tile * 32;
        __builtin_amdgcn_global_load_lds((gv_t*)(u16*)src, (lv_t*)&Bs[dst], 16, 0, 0);
    };

    GEMM_BODY(32)   // K = 1024 -> 32 K-tiles of 32

    // epilogue: C/D col = rr, row = kq*4 + q
    const int rbase = tm * 256 + wr * 128 + kq * 4;
    const int cbase = tn * 256 + wc * 64 + rr;
    const int e = ebase + (tn >> 4);
#pragma unroll
    for (int mi = 0; mi < 8; mi++) {
#pragma unroll
        for (int q = 0; q < 4; q++) {
            const int row = rbase + mi * 16 + q;
            const float wgt = w4[(size_t)row * 4 + e];
            u16* hp = Hout + (size_t)row * ldh + cbase;
#pragma unroll
            for (int nf = 0; nf < 4; nf++)
                hp[nf * 16] = f2bf(wgt * gelu_tanh(acc[mi][nf][q]));
        }
    }
}

// ---------- GEMM2: split-K x4, chunked-swizzle (r12-style) mapping ----------
// Grid 512 = 2 blocks/CU co-resident. split = swz&3 over K (2048 each);
// outputs to one of 4 fp32 partial buffers.
__global__ __launch_bounds__(512, 4) void gemm2_kernel(
    const u16* __restrict__ A, const u16* __restrict__ BT,
    const int lda, const int ldb, const int NITER, const int skoff,
    float* __restrict__ O0, float* __restrict__ O1,
    float* __restrict__ O2, float* __restrict__ O3) {
    __shared__ __align__(16) u16 As[16384];
    __shared__ __align__(16) u16 Bs[16384];
    const int tid = threadIdx.x;
    const int w = tid >> 6, lane = tid & 63;
    const int wr = w >> 2, wc = w & 3;

    const int chunk = gridDim.x >> 3;
    const int swz = ((int)blockIdx.x & 7) * chunk + ((int)blockIdx.x >> 3);
    const int split = swz & 3;
    const int t0_ = swz >> 2;
    const int tm = t0_ >> 2, tn = t0_ & 3;
    const u16* Ab = A  + (size_t)split * skoff;
    const u16* Bb = BT + (size_t)split * skoff;

    const int il = lane >> 3;
    const int cch = (lane & 7) ^ il;
    const int rowoff = il * 2 + (cch >> 2);
    const int kch = cch & 3;
    const u16* gA0 = Ab + (size_t)(tm * 256 + w * 16 + rowoff) * lda + kch * 8;
    const u16* gB0 = Bb + (size_t)(tn * 256 + w * 16 + rowoff) * ldb + kch * 8;

    const int rr = lane & 15, kq = lane >> 4;
    const int lfrag = (rr >> 1) * 64 + (((((rr & 1) << 2) | kq) ^ ((rr >> 1) & 7)) << 3);

    f32x4 acc[8][4];
#pragma unroll
    for (int mi = 0; mi < 8; mi++)
#pragma unroll
        for (int nf = 0; nf < 4; nf++) acc[mi][nf] = (f32x4){0.f, 0.f, 0.f, 0.f};
    bf16x8 a[4], b[4];

    auto stage_a = [&](int tile, int half) {
        const int dst = (tile & 1) * 8192 + half * 4096 + w * 512;
        const u16* src = gA0 + (size_t)half * 128 * lda + (size_t)tile * 32;
        __builtin_amdgcn_global_load_lds((gv_t*)(u16*)src, (lv_t*)&As[dst], 16, 0, 0);
    };
    auto stage_b = [&](int tile, int half) {
        const int dst = (tile & 1) * 8192 + half * 4096 + w * 512;
        const u16* src = gB0 + (size_t)half * 128 * ldb + (size_t)tile * 32;
        __builtin_amdgcn_global_load_lds((gv_t*)(u16*)src, (lv_t*)&Bs[dst], 16, 0, 0);
    };

    GEMM_BODY(NITER)

    const int rbase = tm * 256 + wr * 128 + kq * 4;
    const int cbase = tn * 256 + wc * 64 + rr;
    float* dst = (split == 0) ? O0 : (split == 1) ? O1 : (split == 2) ? O2 : O3;
#pragma unroll
    for (int mi = 0; mi < 8; mi++) {
#pragma unroll
        for (int q = 0; q < 4; q++) {
            const int row = rbase + mi * 16 + q;
            float* op = dst + (size_t)row * 1024 + cbase;
#pragma unroll
            for (int nf = 0; nf < 4; nf++) op[nf * 16] = acc[mi][nf][q];
        }
    }
}

#undef LOADA
#undef LOADB
#undef BAR
#undef MFQ
#undef VMW0
#undef GEMM_BODY

// ---------- launch ----------
extern "C" void kernel_launch(void* const* d_in, const int* in_sizes, int n_in,
                              void* d_out, int out_size, void* d_ws, size_t ws_size,
                              hipStream_t stream) {
    (void)in_sizes; (void)n_in; (void)out_size;
    const float* x  = (const float*)d_in[0];
    const float* Wg = (const float*)d_in[1];
    const float* W1 = (const float*)d_in[2];
    const float* A1 = (const float*)d_in[3];
    const float* B1 = (const float*)d_in[4];
    const float* W2 = (const float*)d_in[5];
    const float* A2 = (const float*)d_in[6];
    const float* B2 = (const float*)d_in[7];
    float* out = (float*)d_out;

    const int N = 8192;

    const size_t need = 131072
                      + (size_t)8192 * 1024 * 2            // Xe
                      + (size_t)8192 * 8192 * 2             // Hs half
                      + (size_t)16384 * 1024 * 2            // W1T
                      + (size_t)1024 * 16384 * 2            // W2T
                      + 4 * (size_t)8192 * 1024 * 4;        // 4 fp32 partials
    if (ws_size < need) return;  // fail visibly rather than corrupt

    char* p = (char*)d_ws;
    float* w4 = (float*)p; p += 131072;
    u16* Xe   = (u16*)p;   p += (size_t)8192 * 1024 * 2;
    u16* Hs   = (u16*)p;   p += (size_t)8192 * 8192 * 2;    // reused across both passes
    u16* W1T  = (u16*)p;   p += (size_t)16384 * 1024 * 2;
    u16* W2T  = (u16*)p;   p += (size_t)1024 * 16384 * 2;
    float* p0 = (float*)p; p += (size_t)8192 * 1024 * 4;
    float* p1 = (float*)p; p += (size_t)8192 * 1024 * 4;
    float* p2 = (float*)p; p += (size_t)8192 * 1024 * 4;
    float* p3 = (float*)p; p += (size_t)8192 * 1024 * 4;

    gate_kernel<<<N / 4, 256, 0, stream>>>(x, Wg, w4);
    cast_x_kernel<<<2048, 256, 0, stream>>>(x, Xe, N * 1024 / 8);
    // W1eff^T[e*4096+f][k] = bf16(W1[e][k][f] + sum_r A1[e][k][r]*B1[e][r][f])
    weff_kernel<<<dim3(128, 32, 4), dim3(32, 8), 0, stream>>>(
        W1, A1, B1, W1T, 4096, 1024,
        (size_t)1024 * 4096, (size_t)1024 * 16, (size_t)16 * 4096, (size_t)4096 * 1024);
    // W2eff^T[d][e*4096+k] = bf16(W2[e][k][d] + sum_r A2[e][k][r]*B2[e][r][d])
    weff_kernel<<<dim3(32, 128, 4), dim3(32, 8), 0, stream>>>(
        W2, A2, B2, W2T, 1024, 16384,
        (size_t)4096 * 1024, (size_t)4096 * 16, (size_t)16 * 1024, (size_t)4096);

    // ---- two LLC-resident passes over the f dimension (8192 cols each) ----
    for (int half = 0; half < 2; ++half) {
        // GEMM1: Hs[m][f'] = bf16(w4[m][e]*gelu(Xe @ W1T_half^T))
        // grid 1024 = 8 XCD x (32 tm x 4 tn_l); 2 blocks/CU co-resident
        gemm1_kernel<<<1024, 512, 0, stream>>>(
            Xe, W1T + (size_t)half * 8192 * 1024, Hs, w4, half * 2);
        // GEMM2: split-K x4 over K=8192 (2048 each); grid 512, 2 blocks/CU
        if (half == 0) {
            gemm2_kernel<<<512, 512, 0, stream>>>(
                Hs, W2T + (size_t)half * 8192, 8192, 16384, 64, 2048, out, p1, p2, p3);
            add3_kernel<<<2048, 256, 0, stream>>>(out, p1, p2, p3, N * 1024 / 4);
        } else {
            gemm2_kernel<<<512, 512, 0, stream>>>(
                Hs, W2T + (size_t)half * 8192, 8192, 16384, 64, 2048, p0, p1, p2, p3);
            add4_kernel<<<2048, 256, 0, stream>>>(out, p0, p1, p2, p3, N * 1024 / 4);
        }
    }
}

// Round 15
// 796.478 us; speedup vs baseline: 5.4987x; 5.4987x over previous
//
#include <hip/hip_runtime.h>
#include <hip/hip_bf16.h>
#include <math.h>
#include <stdint.h>

typedef unsigned short u16;
typedef __bf16 bf16x8 __attribute__((ext_vector_type(8)));
typedef float f32x4 __attribute__((ext_vector_type(4)));
typedef __attribute__((address_space(1))) void gv_t;
typedef __attribute__((address_space(3))) void lv_t;

// ---------- helpers ----------
__device__ inline u16 f2bf(float f) {
    union { float f; uint32_t u; } v; v.f = f;
    uint32_t u = v.u;
    uint32_t r = (u + 0x7fffu + ((u >> 16) & 1u)) >> 16;  // RNE
    return (u16)r;
}
__device__ inline float gelu_tanh(float x) {
    float u = 0.7978845608028654f * x * (1.0f + 0.044715f * x * x);
    float e = __expf(2.0f * u);
    float t = 1.0f - 2.0f / (e + 1.0f);
    return 0.5f * x * (1.0f + t);
}

// ---------- gate ----------
__global__ __launch_bounds__(256) void gate_kernel(const float* __restrict__ x,
                                                   const float* __restrict__ Wg,
                                                   float* __restrict__ w4) {
    const int token = blockIdx.x * 4 + (threadIdx.x >> 6);
    const int lane  = threadIdx.x & 63;
    const float* xr = x + (size_t)token * 1024;
    float acc[16];
#pragma unroll
    for (int e = 0; e < 16; e++) acc[e] = 0.f;
#pragma unroll 4
    for (int d = lane; d < 1024; d += 64) {
        float xv = xr[d];
        const float4* wr_ = (const float4*)(Wg + (size_t)d * 16);
        float4 a0 = wr_[0], a1 = wr_[1], a2 = wr_[2], a3 = wr_[3];
        acc[0]  += xv * a0.x; acc[1]  += xv * a0.y; acc[2]  += xv * a0.z; acc[3]  += xv * a0.w;
        acc[4]  += xv * a1.x; acc[5]  += xv * a1.y; acc[6]  += xv * a1.z; acc[7]  += xv * a1.w;
        acc[8]  += xv * a2.x; acc[9]  += xv * a2.y; acc[10] += xv * a2.z; acc[11] += xv * a2.w;
        acc[12] += xv * a3.x; acc[13] += xv * a3.y; acc[14] += xv * a3.z; acc[15] += xv * a3.w;
    }
#pragma unroll
    for (int e = 0; e < 16; e++) {
        float v = acc[e];
        v += __shfl_xor(v, 32, 64);
        v += __shfl_xor(v, 16, 64);
        v += __shfl_xor(v, 8, 64);
        v += __shfl_xor(v, 4, 64);
        v += __shfl_xor(v, 2, 64);
        v += __shfl_xor(v, 1, 64);
        acc[e] = v;
    }
    if (lane == 0) {
        float l[16];
#pragma unroll
        for (int e = 0; e < 16; e++) l[e] = acc[e];
        int   bi4[4]; float bv4[4];
#pragma unroll
        for (int j = 0; j < 4; j++) {
            int bi = 0; float b = l[0];
#pragma unroll
            for (int e = 1; e < 16; e++) { if (l[e] > b) { b = l[e]; bi = e; } }
            bi4[j] = bi; bv4[j] = b; l[bi] = -INFINITY;
        }
        float mx = bv4[0];
        float den = 0.f;
#pragma unroll
        for (int j = 0; j < 4; j++) den += expf(bv4[j] - mx);
        float wout[4] = {0.f, 0.f, 0.f, 0.f};
#pragma unroll
        for (int j = 0; j < 4; j++)
            if (bi4[j] < 4) wout[bi4[j]] = expf(bv4[j] - mx) / den;
        float* o = w4 + (size_t)token * 4;
        o[0] = wout[0]; o[1] = wout[1]; o[2] = wout[2]; o[3] = wout[3];
    }
}

// ---------- vectorized cast x fp32 -> bf16 ----------
__global__ __launch_bounds__(256) void cast_x_kernel(const float* __restrict__ x,
                                                     u16* __restrict__ Xe, int nvec) {
    for (int i = blockIdx.x * blockDim.x + threadIdx.x; i < nvec; i += gridDim.x * blockDim.x) {
        const float4* s = (const float4*)(x + (size_t)i * 8);
        float4 a = s[0], b = s[1];
        union { u16 h[8]; uint4 q; } o;
        o.h[0] = f2bf(a.x); o.h[1] = f2bf(a.y); o.h[2] = f2bf(a.z); o.h[3] = f2bf(a.w);
        o.h[4] = f2bf(b.x); o.h[5] = f2bf(b.y); o.h[6] = f2bf(b.z); o.h[7] = f2bf(b.w);
        *(uint4*)(Xe + (size_t)i * 8) = o.q;
    }
}

// ---------- fused transpose + LoRA-fold ----------
__global__ __launch_bounds__(256) void weff_kernel(const float* __restrict__ src,
                                                   const float* __restrict__ Am,
                                                   const float* __restrict__ Bm,
                                                   u16* __restrict__ dst,
                                                   int Fdim, int lddst,
                                                   size_t s_est, size_t a_est, size_t b_est, size_t d_est) {
    const int e = blockIdx.z;
    src += e * s_est; Am += e * a_est; Bm += e * b_est; dst += e * d_est;
    __shared__ float t[32][33];
    __shared__ float sa[32][16];
    __shared__ float sb[16][32];
    const int tx = threadIdx.x, ty = threadIdx.y, tid = ty * 32 + tx;
    const int f0 = blockIdx.x * 32, k0 = blockIdx.y * 32;
#pragma unroll
    for (int i = ty; i < 32; i += 8) t[i][tx] = src[(size_t)(k0 + i) * Fdim + f0 + tx];
    for (int idx = tid; idx < 512; idx += 256) sa[idx >> 4][idx & 15] = Am[(size_t)(k0 + (idx >> 4)) * 16 + (idx & 15)];
    for (int idx = tid; idx < 512; idx += 256) sb[idx >> 5][idx & 31] = Bm[(size_t)(idx >> 5) * Fdim + f0 + (idx & 31)];
    __syncthreads();
#pragma unroll
    for (int i = ty; i < 32; i += 8) {
        float s = t[tx][i];
#pragma unroll
        for (int r = 0; r < 16; r++) s += sa[tx][r] * sb[r][i];
        dst[(size_t)(f0 + i) * lddst + k0 + tx] = f2bf(s);
    }
}

// ---------- out += p1 + p2 + p3 ----------
__global__ __launch_bounds__(256) void add3_kernel(float* __restrict__ out,
                                                   const float* __restrict__ p1,
                                                   const float* __restrict__ p2,
                                                   const float* __restrict__ p3, int n4) {
    for (int i = blockIdx.x * blockDim.x + threadIdx.x; i < n4; i += gridDim.x * blockDim.x) {
        float4 o = ((float4*)out)[i];
        float4 a = ((const float4*)p1)[i];
        float4 b = ((const float4*)p2)[i];
        float4 c = ((const float4*)p3)[i];
        o.x += a.x + b.x + c.x; o.y += a.y + b.y + c.y;
        o.z += a.z + b.z + c.z; o.w += a.w + b.w + c.w;
        ((float4*)out)[i] = o;
    }
}

// ================= shared GEMM inner-loop macros (r9, best measured) =================
#define LOADA(BUF, AQ)                                                         \
    _Pragma("unroll") for (int mi = 0; mi < 4; mi++)                           \
    _Pragma("unroll") for (int kh = 0; kh < 2; kh++)                           \
        a[mi][kh] = *(const bf16x8*)&As[(BUF)*16384 + kh*8192 + wr*4096 + (AQ)*2048 + mi*512 + lfrag];
#define LOADB(BUF, BP)                                                         \
    _Pragma("unroll") for (int nf = 0; nf < 2; nf++)                           \
    _Pragma("unroll") for (int kh = 0; kh < 2; kh++)                           \
        b[(BP)*2+nf][kh] = *(const bf16x8*)&Bs[(BUF)*16384 + kh*8192 + wc*2048 + (BP)*1024 + nf*512 + lfrag];
#define BARA __builtin_amdgcn_s_barrier();
#define MFQ(MQ, NP)                                                            \
    __builtin_amdgcn_s_setprio(1);                                             \
    _Pragma("unroll") for (int mi = 0; mi < 4; mi++)                           \
    _Pragma("unroll") for (int nf = 0; nf < 2; nf++)                           \
    _Pragma("unroll") for (int kh = 0; kh < 2; kh++)                           \
        acc[(MQ)*4+mi][(NP)*2+nf] = __builtin_amdgcn_mfma_f32_16x16x32_bf16(   \
            a[mi][kh], b[(NP)*2+nf][kh], acc[(MQ)*4+mi][(NP)*2+nf], 0, 0, 0);  \
    __builtin_amdgcn_s_setprio(0);
#define BARB __builtin_amdgcn_s_barrier();
#define VMW4 asm volatile("s_waitcnt vmcnt(4)" ::: "memory");
#define VMW0 asm volatile("s_waitcnt vmcnt(0)" ::: "memory");

#define GEMM_BODY(NITER)                                                       \
    stage_a(0, 0); stage_a(0, 1); stage_b(0, 0); stage_b(0, 1); stage_b(1, 0); stage_b(1, 1); \
    VMW4                                                                       \
    __builtin_amdgcn_s_barrier();                                              \
    for (int s2 = 0; s2 < (NITER); ++s2) {                                     \
        const int t0 = 2 * s2;                                                 \
        const bool pf = (s2 + 1 < (NITER));                                    \
        LOADA(0, 0) LOADB(0, 0) stage_a(t0 + 1, 0); BARA MFQ(0, 0) BARB        \
        LOADB(0, 1)             stage_a(t0 + 1, 1); BARA MFQ(0, 1) BARB        \
        LOADA(0, 1)  if (pf) stage_b(t0 + 2, 0);    BARA MFQ(1, 0) BARB        \
                     if (pf) stage_b(t0 + 2, 1);    BARA MFQ(1, 1)             \
        if (pf) { VMW4 } else { VMW0 }              BARB                       \
        LOADA(1, 0) LOADB(1, 0) if (pf) stage_a(t0 + 2, 0); BARA MFQ(0, 0) BARB \
        LOADB(1, 1)             if (pf) stage_a(t0 + 2, 1); BARA MFQ(0, 1) BARB \
        LOADA(1, 1)             if (pf) stage_b(t0 + 3, 0); BARA MFQ(1, 0) BARB \
                                if (pf) stage_b(t0 + 3, 1); BARA MFQ(1, 1)     \
        if (pf) { VMW4 }                                    BARB               \
    }

// ---------- GEMM1: Hout = bf16(w4*gelu(A @ BT^T)); r9 loop + r10 XCD-owned mapping ----------
// Grid 1024 = 8 XCD x 128 locals; tn = xcd*4 + (local&3), tm = local>>2.
// Per XCD the 4 owned W1T panels (2 MB) stay L2-resident across all tm rounds
// (r10/r12 evidence: FETCH 270 -> 99 MB, 221 -> 200 us).
__global__ __launch_bounds__(512, 2) void gemm1_kernel(
    const u16* __restrict__ A, const u16* __restrict__ BT,
    u16* __restrict__ Hout, const float* __restrict__ w4, const int ebase) {
    const int lda = 1024, ldb = 1024, ldh = 8192;
    __shared__ __align__(16) u16 As[32768];
    __shared__ __align__(16) u16 Bs[32768];
    const int tid = threadIdx.x;
    const int w = tid >> 6, lane = tid & 63;
    const int wr = w >> 2, wc = w & 3;

    const int xcd = (int)blockIdx.x & 7;
    const int local = (int)blockIdx.x >> 3;
    const int tn = xcd * 4 + (local & 3);
    const int tm = local >> 2;

    // staging addressing (linear LDS dest, inverse-swizzled global source)
    const int il = lane >> 3;
    const int cch = (lane & 7) ^ il;
    const int rowoff = il * 2 + (cch >> 2);
    const int kch = cch & 3;
    const u16* gA0 = A  + (size_t)(tm * 256 + w * 16 + rowoff) * lda + kch * 8;
    const u16* gB0 = BT + (size_t)(tn * 256 + w * 16 + rowoff) * ldb + kch * 8;

    // fragment read lane offset
    const int rr = lane & 15, kq = lane >> 4;
    const int lfrag = (rr >> 1) * 64 + (((((rr & 1) << 2) | kq) ^ ((rr >> 1) & 7)) << 3);

    f32x4 acc[8][4];
#pragma unroll
    for (int mi = 0; mi < 8; mi++)
#pragma unroll
        for (int nf = 0; nf < 4; nf++) acc[mi][nf] = (f32x4){0.f, 0.f, 0.f, 0.f};
    bf16x8 a[4][2], b[4][2];

    auto stage_a = [&](int tile, int half) {
        const int dst = (tile & 1) * 16384 + half * 4096 + w * 512;
        const u16* src = gA0 + (size_t)half * 128 * lda + (size_t)tile * 64;
        __builtin_amdgcn_global_load_lds((gv_t*)(u16*)src,        (lv_t*)&As[dst],        16, 0, 0);
        __builtin_amdgcn_global_load_lds((gv_t*)(u16*)(src + 32), (lv_t*)&As[dst + 8192], 16, 0, 0);
    };
    auto stage_b = [&](int tile, int half) {
        const int dst = (tile & 1) * 16384 + half * 4096 + w * 512;
        const u16* src = gB0 + (size_t)half * 128 * ldb + (size_t)tile * 64;
        __builtin_amdgcn_global_load_lds((gv_t*)(u16*)src,        (lv_t*)&Bs[dst],        16, 0, 0);
        __builtin_amdgcn_global_load_lds((gv_t*)(u16*)(src + 32), (lv_t*)&Bs[dst + 8192], 16, 0, 0);
    };

    GEMM_BODY(8)   // K = 1024 -> 16 K-tiles

    // epilogue: C/D col = rr, row = kq*4 + q
    const int rbase = tm * 256 + wr * 128 + kq * 4;
    const int cbase = tn * 256 + wc * 64 + rr;
    const int e = ebase + (tn >> 4);
#pragma unroll
    for (int mi = 0; mi < 8; mi++) {
#pragma unroll
        for (int q = 0; q < 4; q++) {
            const int row = rbase + mi * 16 + q;
            const float wgt = w4[(size_t)row * 4 + e];
            u16* hp = Hout + (size_t)row * ldh + cbase;
#pragma unroll
            for (int nf = 0; nf < 4; nf++)
                hp[nf * 16] = f2bf(wgt * gelu_tanh(acc[mi][nf][q]));
        }
    }
}

// ---------- GEMM2 (r9 verbatim): (split?Part:Out) = A @ BT^T, split-K x2 ----------
__global__ __launch_bounds__(512, 2) void gemm2_kernel(
    const u16* __restrict__ A, const u16* __restrict__ BT,
    const int lda, const int ldb, const int ntn, const int NITER, const int skoff,
    float* __restrict__ Out, float* __restrict__ Part) {
    __shared__ __align__(16) u16 As[32768];
    __shared__ __align__(16) u16 Bs[32768];
    const int tid = threadIdx.x;
    const int w = tid >> 6, lane = tid & 63;
    const int wr = w >> 2, wc = w & 3;

    const int chunk = gridDim.x >> 3;
    const int swz = ((int)blockIdx.x & 7) * chunk + ((int)blockIdx.x >> 3);
    const int split = swz & 1;
    const int t = swz >> 1;
    const int tm = t / ntn, tn = t % ntn;
    const u16* Ab = A  + (size_t)split * skoff;
    const u16* Bb = BT + (size_t)split * skoff;

    const int il = lane >> 3;
    const int cch = (lane & 7) ^ il;
    const int rowoff = il * 2 + (cch >> 2);
    const int kch = cch & 3;
    const u16* gA0 = Ab + (size_t)(tm * 256 + w * 16 + rowoff) * lda + kch * 8;
    const u16* gB0 = Bb + (size_t)(tn * 256 + w * 16 + rowoff) * ldb + kch * 8;

    const int rr = lane & 15, kq = lane >> 4;
    const int lfrag = (rr >> 1) * 64 + (((((rr & 1) << 2) | kq) ^ ((rr >> 1) & 7)) << 3);

    f32x4 acc[8][4];
#pragma unroll
    for (int mi = 0; mi < 8; mi++)
#pragma unroll
        for (int nf = 0; nf < 4; nf++) acc[mi][nf] = (f32x4){0.f, 0.f, 0.f, 0.f};
    bf16x8 a[4][2], b[4][2];

    auto stage_a = [&](int tile, int half) {
        const int dst = (tile & 1) * 16384 + half * 4096 + w * 512;
        const u16* src = gA0 + (size_t)half * 128 * lda + (size_t)tile * 64;
        __builtin_amdgcn_global_load_lds((gv_t*)(u16*)src,        (lv_t*)&As[dst],        16, 0, 0);
        __builtin_amdgcn_global_load_lds((gv_t*)(u16*)(src + 32), (lv_t*)&As[dst + 8192], 16, 0, 0);
    };
    auto stage_b = [&](int tile, int half) {
        const int dst = (tile & 1) * 16384 + half * 4096 + w * 512;
        const u16* src = gB0 + (size_t)half * 128 * ldb + (size_t)tile * 64;
        __builtin_amdgcn_global_load_lds((gv_t*)(u16*)src,        (lv_t*)&Bs[dst],        16, 0, 0);
        __builtin_amdgcn_global_load_lds((gv_t*)(u16*)(src + 32), (lv_t*)&Bs[dst + 8192], 16, 0, 0);
    };

    GEMM_BODY(NITER)

    const int rbase = tm * 256 + wr * 128 + kq * 4;
    const int cbase = tn * 256 + wc * 64 + rr;
    float* dst = split ? Part : Out;
#pragma unroll
    for (int mi = 0; mi < 8; mi++) {
#pragma unroll
        for (int q = 0; q < 4; q++) {
            const int row = rbase + mi * 16 + q;
            float* op = dst + (size_t)row * 1024 + cbase;
#pragma unroll
            for (int nf = 0; nf < 4; nf++) op[nf * 16] = acc[mi][nf][q];
        }
    }
}

#undef LOADA
#undef LOADB
#undef BARA
#undef MFQ
#undef BARB
#undef VMW4
#undef VMW0
#undef GEMM_BODY

// ---------- launch ----------
extern "C" void kernel_launch(void* const* d_in, const int* in_sizes, int n_in,
                              void* d_out, int out_size, void* d_ws, size_t ws_size,
                              hipStream_t stream) {
    (void)in_sizes; (void)n_in; (void)out_size;
    const float* x  = (const float*)d_in[0];
    const float* Wg = (const float*)d_in[1];
    const float* W1 = (const float*)d_in[2];
    const float* A1 = (const float*)d_in[3];
    const float* B1 = (const float*)d_in[4];
    const float* W2 = (const float*)d_in[5];
    const float* A2 = (const float*)d_in[6];
    const float* B2 = (const float*)d_in[7];
    float* out = (float*)d_out;

    const int N = 8192;

    const size_t need = 131072
                      + (size_t)8192 * 1024 * 2            // Xe
                      + (size_t)8192 * 8192 * 2             // Hs half
                      + (size_t)16384 * 1024 * 2            // W1T
                      + (size_t)1024 * 16384 * 2            // W2T
                      + 3 * (size_t)8192 * 1024 * 4;        // 3 fp32 partials
    if (ws_size < need) return;  // fail visibly rather than corrupt

    char* p = (char*)d_ws;
    float* w4 = (float*)p; p += 131072;
    u16* Xe   = (u16*)p;   p += (size_t)8192 * 1024 * 2;
    u16* Hs   = (u16*)p;   p += (size_t)8192 * 8192 * 2;    // reused across both passes
    u16* W1T  = (u16*)p;   p += (size_t)16384 * 1024 * 2;
    u16* W2T  = (u16*)p;   p += (size_t)1024 * 16384 * 2;
    float* p1 = (float*)p; p += (size_t)8192 * 1024 * 4;
    float* p2 = (float*)p; p += (size_t)8192 * 1024 * 4;
    float* p3 = (float*)p; p += (size_t)8192 * 1024 * 4;

    gate_kernel<<<N / 4, 256, 0, stream>>>(x, Wg, w4);
    cast_x_kernel<<<2048, 256, 0, stream>>>(x, Xe, N * 1024 / 8);
    // W1eff^T[e*4096+f][k] = bf16(W1[e][k][f] + sum_r A1[e][k][r]*B1[e][r][f])
    weff_kernel<<<dim3(128, 32, 4), dim3(32, 8), 0, stream>>>(
        W1, A1, B1, W1T, 4096, 1024,
        (size_t)1024 * 4096, (size_t)1024 * 16, (size_t)16 * 4096, (size_t)4096 * 1024);
    // W2eff^T[d][e*4096+k] = bf16(W2[e][k][d] + sum_r A2[e][k][r]*B2[e][r][d])
    weff_kernel<<<dim3(32, 128, 4), dim3(32, 8), 0, stream>>>(
        W2, A2, B2, W2T, 1024, 16384,
        (size_t)4096 * 1024, (size_t)4096 * 16, (size_t)16 * 1024, (size_t)4096);

    // ---- two LLC-resident passes over the f dimension (8192 cols each) ----
    for (int half = 0; half < 2; ++half) {
        // GEMM1 (this half): Hs[m][f'] = bf16(w4[m][e]*gelu(Xe @ W1T_half^T))
        // grid 1024 = 8 XCD x (32 tm x 4 tn_l); r9 loop + XCD-owned tn mapping
        gemm1_kernel<<<1024, 512, 0, stream>>>(
            Xe, W1T + (size_t)half * 8192 * 1024, Hs, w4, half * 2);
        // GEMM2 (this half): split-K x2 over K=8192 (4096 each); grid 2x32x4
        float* o0 = (half == 0) ? out : p2;
        float* o1 = (half == 0) ? p1  : p3;
        gemm2_kernel<<<256, 512, 0, stream>>>(
            Hs, W2T + (size_t)half * 8192, 8192, 16384, 4, 32, 4096, o0, o1);
    }
    add3_kernel<<<2048, 256, 0, stream>>>(out, p1, p2, p3, N * 1024 / 4);
}